// Round 4
// baseline (59.345 us; speedup 1.0000x reference)
//
#include <hip/hip_runtime.h>

// MeanAggregator: out[n, :] = (1/K) * sum_{k<K} features[idx[n,k], :]
// N=100000, K=6, V=200000, D=128, fp32.
//
// Round 4: depth-2 software pipeline. Two nodes per slot in alternating
// register buffers (vA/vB), manually unrolled so all register indexing is
// static. While node A's accumulate waits on its 6 gathers, node B's 6
// gathers and the next index loads are already in flight -> 2x outstanding
// bytes per wave, no full vmcnt drain per node.
//
// Layout: 32 lanes per node-slot, lane owns one f32x4 (16B) of the 512B row.
// 256 threads/block -> 8 slots/block; persistent grid of 2048 blocks.

typedef float f32x4 __attribute__((ext_vector_type(4)));

#define K_NEIGH 6
#define D_FEAT 128
#define SLOTS_PER_BLOCK 8

__global__ __launch_bounds__(256) void MeanAggregator_16415365005349_kernel(
    const float* __restrict__ feat,
    const int* __restrict__ idx,
    float* __restrict__ out,
    int N) {
  const int slot = threadIdx.x >> 5;
  const int lane = threadIdx.x & 31;
  const int stride = gridDim.x * SLOTS_PER_BLOCK;

  int n = blockIdx.x * SLOTS_PER_BLOCK + slot;  // stage-A node
  if (n >= N) return;

  int rA[K_NEIGH], rB[K_NEIGH];
  f32x4 vA[K_NEIGH], vB[K_NEIGH];

  // Prologue: idx A, issue gathers A, idx B (clamped).
#pragma unroll
  for (int k = 0; k < K_NEIGH; ++k) rA[k] = idx[(size_t)n * K_NEIGH + k];
#pragma unroll
  for (int k = 0; k < K_NEIGH; ++k)
    vA[k] = reinterpret_cast<const f32x4*>(feat + (size_t)rA[k] * D_FEAT)[lane];
  {
    const int nb = (n + stride < N) ? (n + stride) : n;
#pragma unroll
    for (int k = 0; k < K_NEIGH; ++k) rB[k] = idx[(size_t)nb * K_NEIGH + k];
  }

  const float s = 1.0f / (float)K_NEIGH;

  while (true) {
    // ---- stage 1: issue B gathers, prefetch idx for n+2*stride, finish A.
#pragma unroll
    for (int k = 0; k < K_NEIGH; ++k)
      vB[k] = reinterpret_cast<const f32x4*>(feat + (size_t)rB[k] * D_FEAT)[lane];

    const int nA2 = n + 2 * stride;
    {
      const int nc = (nA2 < N) ? nA2 : n;
#pragma unroll
      for (int k = 0; k < K_NEIGH; ++k) rA[k] = idx[(size_t)nc * K_NEIGH + k];
    }

    {
      f32x4 acc = vA[0];
#pragma unroll
      for (int k = 1; k < K_NEIGH; ++k) acc += vA[k];
      acc *= s;
      __builtin_nontemporal_store(
          acc, reinterpret_cast<f32x4*>(out + (size_t)n * D_FEAT) + lane);
    }
    if (n + stride >= N) return;

    // ---- stage 2: issue next-A gathers, prefetch idx for n+3*stride, finish B.
#pragma unroll
    for (int k = 0; k < K_NEIGH; ++k)
      vA[k] = reinterpret_cast<const f32x4*>(feat + (size_t)rA[k] * D_FEAT)[lane];

    const int nB2 = n + 3 * stride;
    {
      const int nc = (nB2 < N) ? nB2 : n;
#pragma unroll
      for (int k = 0; k < K_NEIGH; ++k) rB[k] = idx[(size_t)nc * K_NEIGH + k];
    }

    {
      f32x4 acc = vB[0];
#pragma unroll
      for (int k = 1; k < K_NEIGH; ++k) acc += vB[k];
      acc *= s;
      __builtin_nontemporal_store(
          acc, reinterpret_cast<f32x4*>(out + (size_t)(n + stride) * D_FEAT) + lane);
    }
    if (nA2 >= N) return;
    n = nA2;
  }
}

extern "C" void kernel_launch(void* const* d_in, const int* in_sizes, int n_in,
                              void* d_out, int out_size, void* d_ws, size_t ws_size,
                              hipStream_t stream) {
  const float* feat = (const float*)d_in[0];   // [V, D] fp32
  const int* idx = (const int*)d_in[1];        // [N, K] int (harness-cast)
  float* out = (float*)d_out;                  // [N, D] fp32

  const int N = in_sizes[1] / K_NEIGH;         // 100000

  const int max_blocks = 2048;                 // 8 blocks/CU * 256 CUs
  int blocks = (N + SLOTS_PER_BLOCK - 1) / SLOTS_PER_BLOCK;
  if (blocks > max_blocks) blocks = max_blocks;

  hipLaunchKernelGGL(MeanAggregator_16415365005349_kernel,
                     dim3(blocks), dim3(256), 0, stream,
                     feat, idx, out, N);
}

// Round 5
// 55.292 us; speedup vs baseline: 1.0733x; 1.0733x over previous
//
#include <hip/hip_runtime.h>

// MeanAggregator: out[n, :] = (1/K) * sum_{k<K} features[idx[n,k], :]
// N=100000, K=6, V=200000, D=128, fp32.
//
// FINAL (revert to Round-1 structure, the best-measured variant):
// 32 lanes per node, lane owns one float4 (16B) of the 512B row; every
// gather is a fully-coalesced 512B segment. 256 threads/block -> 8
// nodes/block, one-shot grid.
//
// Why no further tricks (measured r1-r4): persistent grid, index
// prefetch pipelining, depth-2 register double-buffering, and
// non-temporal stores all landed within noise or regressed. The kernel
// runs at ~2.33 TB/s L2-miss fetch rate (146 MB / 63 us) across all
// structures = ~95% of the 8-XCD line-rate ceiling (8 x 128 B x 2.4 GHz
// = 2.46 TB/s), with VALUBusy ~5%, MfmaUtil 0, occupancy non-binding.
// Fetch bytes (146 MB) are 1.4x the unique-line floor (~100 MB); the
// gap is cross-XCD duplication + L2 capacity (32 MB << 102 MB table),
// and any restructuring to capture it (index binning, inversion,
// bf16 staging) costs more combine/convert traffic than it saves.

#define K_NEIGH 6
#define D_FEAT 128
#define NODES_PER_BLOCK 8

__global__ __launch_bounds__(256) void MeanAggregator_16415365005349_kernel(
    const float* __restrict__ feat,
    const int* __restrict__ idx,
    float* __restrict__ out,
    int N) {
  const int node = blockIdx.x * NODES_PER_BLOCK + (threadIdx.x >> 5);
  const int lane = threadIdx.x & 31;
  if (node >= N) return;

  // All 6 indices first (same address across the node's 32 lanes -> cache
  // broadcast), then all 6 row loads back-to-back so 6 independent 16B
  // loads per lane are in flight together.
  int r[K_NEIGH];
#pragma unroll
  for (int k = 0; k < K_NEIGH; ++k) r[k] = idx[(size_t)node * K_NEIGH + k];

  float4 v[K_NEIGH];
#pragma unroll
  for (int k = 0; k < K_NEIGH; ++k) {
    v[k] = reinterpret_cast<const float4*>(feat + (size_t)r[k] * D_FEAT)[lane];
  }

  float4 acc = v[0];
#pragma unroll
  for (int k = 1; k < K_NEIGH; ++k) {
    acc.x += v[k].x; acc.y += v[k].y; acc.z += v[k].z; acc.w += v[k].w;
  }
  const float s = 1.0f / (float)K_NEIGH;
  acc.x *= s; acc.y *= s; acc.z *= s; acc.w *= s;

  reinterpret_cast<float4*>(out + (size_t)node * D_FEAT)[lane] = acc;
}

extern "C" void kernel_launch(void* const* d_in, const int* in_sizes, int n_in,
                              void* d_out, int out_size, void* d_ws, size_t ws_size,
                              hipStream_t stream) {
  const float* feat = (const float*)d_in[0];   // [V, D] fp32
  const int* idx = (const int*)d_in[1];        // [N, K] int (harness-cast)
  float* out = (float*)d_out;                  // [N, D] fp32

  const int N = in_sizes[1] / K_NEIGH;         // 100000
  const int blocks = (N + NODES_PER_BLOCK - 1) / NODES_PER_BLOCK;
  hipLaunchKernelGGL(MeanAggregator_16415365005349_kernel,
                     dim3(blocks), dim3(256), 0, stream,
                     feat, idx, out, N);
}